// Round 5
// baseline (368.528 us; speedup 1.0000x reference)
//
#include <hip/hip_runtime.h>
#include <hip/hip_bf16.h>

#define T_ 8
#define H_ 96
#define W_ 160
#define C_ 256
#define F_ 256
#define M_ (T_ * H_ * W_)   // 122880

typedef __bf16 bf16_t;
typedef __bf16 bf16x4 __attribute__((ext_vector_type(4)));
typedef __bf16 bf16x8 __attribute__((ext_vector_type(8)));
typedef float  f32x4  __attribute__((ext_vector_type(4)));

// ---------------- pass 0: WpT[f][c] = bf16(Wp[c][f]) ----------------
__global__ void wp_transpose_kernel(const float* __restrict__ Wp,
                                    bf16_t* __restrict__ WpT) {
    int f = blockIdx.x;   // 0..255
    int c = threadIdx.x;  // 0..255
    WpT[f * C_ + c] = (bf16_t)Wp[c * F_ + f];
}

// ---------------- pass 1: depthwise 3x3x3 conv, fp32 -> bf16 ----------------
// block = h-pair x w-quad; 4 waves, wave w = one w; lane = channel-quad
// (64 lanes x 4ch = full C per wave). f32x4 loads: 16B/lane, 1KB/instr.
// Weights staged in LDS once per block; read via ds_read_b128 (lgkm pipe),
// keeping the vmem path for x only. ~2.3x fewer vmem instructions than r4.
__global__ __launch_bounds__(256, 4) void dw_conv_kernel(const float* __restrict__ x,
                                                         const float* __restrict__ Wd,
                                                         bf16_t* __restrict__ dw) {
    __shared__ float Ws[27 * C_];     // 27648 B

    // stage weights (27*64 f32x4 slots over 256 threads)
    for (int i = threadIdx.x; i < 27 * 64; i += 256) {
        int k = i >> 6, q = i & 63;
        *(f32x4*)&Ws[k * C_ + q * 4] = *(const f32x4*)&Wd[k * C_ + q * 4];
    }
    __syncthreads();

    // XCD-chunked swizzle: grid 1920 % 8 == 0 -> bijective
    int nchunk = gridDim.x >> 3;
    int bb  = (blockIdx.x & 7) * nchunk + (blockIdx.x >> 3);
    int h2  = bb / (W_ / 4);
    int wq  = bb % (W_ / 4);
    int h0  = h2 * 2;
    int tid = threadIdx.x;
    int c   = (tid & 63) * 4;        // channel quad (lane)
    int w   = wq * 4 + (tid >> 6);   // wave-uniform

    f32x4 acc[2][8] = {};
    const int tstride = H_ * W_ * C_;

#pragma unroll
    for (int dh = -1; dh <= 2; ++dh) {
        int hh = h0 + dh;
        if (hh < 0 || hh >= H_) continue;          // block-uniform

        // ---- batch-issue x loads for this dh (3 ww x 8 tt, f32x4) ----
        f32x4 v[3][8];
#pragma unroll
        for (int dwi = -1; dwi <= 1; ++dwi) {
            int ww = w + dwi;
            const float* px = x + (hh * W_ + ww) * C_ + c;
#pragma unroll
            for (int tt = 0; tt < 8; ++tt) {
                f32x4 vv = {};
                if ((unsigned)ww < (unsigned)W_)   // wave-uniform
                    vv = *(const f32x4*)&px[tt * tstride];
                v[dwi + 1][tt] = vv;
            }
        }

        // ---- weights for this dh from LDS: kh = dh+1-j ----
        f32x4 wv[2][3][3];
#pragma unroll
        for (int j = 0; j < 2; ++j) {
            int kh = dh + 1 - j;
            if (kh < 0 || kh > 2) continue;        // compile-time
#pragma unroll
            for (int kt = 0; kt < 3; ++kt)
#pragma unroll
                for (int kw = 0; kw < 3; ++kw)
                    wv[j][kt][kw] = *(const f32x4*)&Ws[((kt * 3 + kh) * 3 + kw) * C_ + c];
        }

        // ---- consume ----
#pragma unroll
        for (int tt = 0; tt < 8; ++tt)
#pragma unroll
            for (int j = 0; j < 2; ++j) {
                int kh = dh + 1 - j;
                if (kh < 0 || kh > 2) continue;    // compile-time
#pragma unroll
                for (int kt = 0; kt < 3; ++kt) {
                    int to = tt + 1 - kt;
                    if (to < 0 || to >= 8) continue;  // compile-time
#pragma unroll
                    for (int kw = 0; kw < 3; ++kw)
                        acc[j][to] += v[kw][tt] * wv[j][kt][kw];
                }
            }
    }

#pragma unroll
    for (int j = 0; j < 2; ++j)
#pragma unroll
        for (int tt = 0; tt < 8; ++tt) {
            bf16x4 o;
#pragma unroll
            for (int q = 0; q < 4; ++q) o[q] = (bf16_t)acc[j][tt][q];
            *(bf16x4*)&dw[((tt * H_ + (h0 + j)) * W_ + w) * C_ + c] = o;
        }
}

// ---------------- pass 2: GEMM [M,256]x[256,256] bf16 MFMA + ReLU ----------------
#define BM 128
#define BN 128
#define BK 32
#define LDSTR 40  // 32 + 8 pad: fragment ds_read_b128 2-way (free) instead of 8-way

__global__ __launch_bounds__(256) void gemm_kernel(const bf16_t* __restrict__ A,   // dw  [M][C]
                                                   const bf16_t* __restrict__ Bt,  // WpT [F][C] (n-major)
                                                   float* __restrict__ out) {      // [M][F]
    __shared__ __align__(16) bf16_t As[BM * LDSTR];
    __shared__ __align__(16) bf16_t Bs[BN * LDSTR];

    int m0   = blockIdx.x * BM;
    int n0   = blockIdx.y * BN;
    int tid  = threadIdx.x;
    int lane = tid & 63;
    int wid  = tid >> 6;
    int wr   = wid >> 1;   // 0..1
    int wc   = wid & 1;    // 0..1
    int r16  = lane & 15;
    int kg   = lane >> 4;  // 0..3

    f32x4 acc[4][4] = {};

    for (int k0 = 0; k0 < C_; k0 += BK) {
        __syncthreads();
#pragma unroll
        for (int it = 0; it < 2; ++it) {
            int slot = tid + it * 256;       // 0..511
            int row  = slot >> 2;            // 0..127
            int seg  = slot & 3;             // 0..3 (8 bf16 each)
            uint4 va = *(const uint4*)&A[(long)(m0 + row) * C_ + k0 + seg * 8];
            *(uint4*)&As[row * LDSTR + seg * 8] = va;
            uint4 vb = *(const uint4*)&Bt[(n0 + row) * C_ + k0 + seg * 8];
            *(uint4*)&Bs[row * LDSTR + seg * 8] = vb;
        }
        __syncthreads();

        bf16x8 af[4], bfr[4];
#pragma unroll
        for (int m = 0; m < 4; ++m)
            af[m] = *(const bf16x8*)&As[(wr * 64 + m * 16 + r16) * LDSTR + kg * 8];
#pragma unroll
        for (int n = 0; n < 4; ++n)
            bfr[n] = *(const bf16x8*)&Bs[(wc * 64 + n * 16 + r16) * LDSTR + kg * 8];

#pragma unroll
        for (int m = 0; m < 4; ++m)
#pragma unroll
            for (int n = 0; n < 4; ++n)
                acc[m][n] = __builtin_amdgcn_mfma_f32_16x16x32_bf16(af[m], bfr[n], acc[m][n], 0, 0, 0);
    }

    // epilogue: ReLU + fp32 store.  D layout: row=(l>>4)*4+r, col=l&15
    int rbase = m0 + wr * 64 + kg * 4;
    int cbase = n0 + wc * 64 + r16;
#pragma unroll
    for (int m = 0; m < 4; ++m)
#pragma unroll
        for (int n = 0; n < 4; ++n)
#pragma unroll
            for (int r = 0; r < 4; ++r) {
                float v = acc[m][n][r];
                v = v > 0.f ? v : 0.f;
                out[(long)(rbase + m * 16 + r) * F_ + cbase + n * 16] = v;
            }
}

extern "C" void kernel_launch(void* const* d_in, const int* in_sizes, int n_in,
                              void* d_out, int out_size, void* d_ws, size_t ws_size,
                              hipStream_t stream) {
    const float* x  = (const float*)d_in[0];
    const float* Wd = (const float*)d_in[1];
    const float* Wp = (const float*)d_in[2];
    float* out = (float*)d_out;

    bf16_t* dw  = (bf16_t*)d_ws;                                  // M_*C_ bf16 = 62,914,560 B
    bf16_t* WpT = (bf16_t*)((char*)d_ws + (size_t)M_ * C_ * 2);   // + 131,072 B

    wp_transpose_kernel<<<F_, C_, 0, stream>>>(Wp, WpT);
    dw_conv_kernel<<<(H_ / 2) * (W_ / 4), 256, 0, stream>>>(x, Wd, dw);
    gemm_kernel<<<dim3(M_ / BM, F_ / BN), 256, 0, stream>>>(dw, WpT, out);
}

// Round 6
// 139.612 us; speedup vs baseline: 2.6397x; 2.6397x over previous
//
#include <hip/hip_runtime.h>
#include <hip/hip_bf16.h>

#define T_ 8
#define H_ 96
#define W_ 160
#define C_ 256
#define F_ 256
#define M_ (T_ * H_ * W_)   // 122880

typedef __bf16 bf16_t;
typedef __bf16 bf16x2 __attribute__((ext_vector_type(2)));
typedef __bf16 bf16x8 __attribute__((ext_vector_type(8)));
typedef float  f32x2  __attribute__((ext_vector_type(2)));
typedef float  f32x4  __attribute__((ext_vector_type(4)));

// ---------------- pass 0: WpT[f][c] = bf16(Wp[c][f]) ----------------
__global__ void wp_transpose_kernel(const float* __restrict__ Wp,
                                    bf16_t* __restrict__ WpT) {
    int f = blockIdx.x;   // 0..255
    int c = threadIdx.x;  // 0..255
    WpT[f * C_ + c] = (bf16_t)Wp[c * F_ + f];
}

// ---------------- pass 1: depthwise 3x3x3 conv, fp32 -> bf16 ----------------
// r3 structure (f32x2 channel-pairs, h-pair x w-pair block) with the latency
// fix: per-dh batch of 24 loads issued back-to-back in source order, weights
// resident in registers (loaded ONCE), and __launch_bounds__(256,2) so the
// 256-VGPR cap never forces the compiler to trim the batch or sink loads.
// Peak live regs ~154 (54 wreg + 32 acc + 48 batch + addr) -> no spill.
__global__ __launch_bounds__(256, 2) void dw_conv_kernel(const float* __restrict__ x,
                                                         const float* __restrict__ Wd,
                                                         bf16_t* __restrict__ dw) {
    // XCD-chunked swizzle: grid 3840 % 8 == 0 -> bijective
    int nchunk = gridDim.x >> 3;
    int bb  = (blockIdx.x & 7) * nchunk + (blockIdx.x >> 3);
    int h2  = bb / (W_ / 2);
    int wq  = bb % (W_ / 2);
    int h0  = h2 * 2;
    int tid = threadIdx.x;
    int c   = (tid & 127) * 2;       // channel pair
    int w   = wq * 2 + (tid >> 7);   // wave-uniform

    // ---- weights: all 27 taps resident (54 VGPRs) ----
    f32x2 wreg[27];
#pragma unroll
    for (int k = 0; k < 27; ++k) wreg[k] = *(const f32x2*)&Wd[k * C_ + c];

    f32x2 acc[2][8] = {};
    const int tstride = H_ * W_ * C_;

#pragma unroll
    for (int dh = -1; dh <= 2; ++dh) {
        int hh = h0 + dh;
        if (hh < 0 || hh >= H_) continue;          // wave-uniform

        // ---- batch-issue all 24 x loads for this dh (3 ww x 8 tt, f32x2) ----
        f32x2 v[3][8];
#pragma unroll
        for (int dwi = -1; dwi <= 1; ++dwi) {
            int ww = w + dwi;
            const float* px = x + (hh * W_ + ww) * C_ + c;
#pragma unroll
            for (int tt = 0; tt < 8; ++tt) {
                f32x2 vv = {};
                if ((unsigned)ww < (unsigned)W_)   // wave-uniform
                    vv = *(const f32x2*)&px[tt * tstride];
                v[dwi + 1][tt] = vv;
            }
        }

        // ---- consume against resident weights ----
#pragma unroll
        for (int tt = 0; tt < 8; ++tt)
#pragma unroll
            for (int j = 0; j < 2; ++j) {
                int kh = dh + 1 - j;
                if (kh < 0 || kh > 2) continue;    // compile-time
#pragma unroll
                for (int kt = 0; kt < 3; ++kt) {
                    int to = tt + 1 - kt;
                    if (to < 0 || to >= 8) continue;  // compile-time
#pragma unroll
                    for (int kw = 0; kw < 3; ++kw)
                        acc[j][to] += v[kw][tt] * wreg[(kt * 3 + kh) * 3 + kw];
                }
            }
    }

#pragma unroll
    for (int j = 0; j < 2; ++j)
#pragma unroll
        for (int tt = 0; tt < 8; ++tt) {
            bf16x2 o;
            o[0] = (bf16_t)acc[j][tt][0];
            o[1] = (bf16_t)acc[j][tt][1];
            *(bf16x2*)&dw[((tt * H_ + (h0 + j)) * W_ + w) * C_ + c] = o;
        }
}

// ---------------- pass 2: GEMM [M,256]x[256,256] bf16 MFMA + ReLU ----------------
#define BM 128
#define BN 128
#define BK 32
#define LDSTR 40  // 32 + 8 pad: fragment ds_read_b128 2-way (free) instead of 8-way

__global__ __launch_bounds__(256) void gemm_kernel(const bf16_t* __restrict__ A,   // dw  [M][C]
                                                   const bf16_t* __restrict__ Bt,  // WpT [F][C] (n-major)
                                                   float* __restrict__ out) {      // [M][F]
    __shared__ __align__(16) bf16_t As[BM * LDSTR];
    __shared__ __align__(16) bf16_t Bs[BN * LDSTR];

    int m0   = blockIdx.x * BM;
    int n0   = blockIdx.y * BN;
    int tid  = threadIdx.x;
    int lane = tid & 63;
    int wid  = tid >> 6;
    int wr   = wid >> 1;   // 0..1
    int wc   = wid & 1;    // 0..1
    int r16  = lane & 15;
    int kg   = lane >> 4;  // 0..3

    f32x4 acc[4][4] = {};

    for (int k0 = 0; k0 < C_; k0 += BK) {
        __syncthreads();
#pragma unroll
        for (int it = 0; it < 2; ++it) {
            int slot = tid + it * 256;       // 0..511
            int row  = slot >> 2;            // 0..127
            int seg  = slot & 3;             // 0..3 (8 bf16 each)
            uint4 va = *(const uint4*)&A[(long)(m0 + row) * C_ + k0 + seg * 8];
            *(uint4*)&As[row * LDSTR + seg * 8] = va;
            uint4 vb = *(const uint4*)&Bt[(n0 + row) * C_ + k0 + seg * 8];
            *(uint4*)&Bs[row * LDSTR + seg * 8] = vb;
        }
        __syncthreads();

        bf16x8 af[4], bfr[4];
#pragma unroll
        for (int m = 0; m < 4; ++m)
            af[m] = *(const bf16x8*)&As[(wr * 64 + m * 16 + r16) * LDSTR + kg * 8];
#pragma unroll
        for (int n = 0; n < 4; ++n)
            bfr[n] = *(const bf16x8*)&Bs[(wc * 64 + n * 16 + r16) * LDSTR + kg * 8];

#pragma unroll
        for (int m = 0; m < 4; ++m)
#pragma unroll
            for (int n = 0; n < 4; ++n)
                acc[m][n] = __builtin_amdgcn_mfma_f32_16x16x32_bf16(af[m], bfr[n], acc[m][n], 0, 0, 0);
    }

    // epilogue: ReLU + fp32 store.  D layout: row=(l>>4)*4+r, col=l&15
    int rbase = m0 + wr * 64 + kg * 4;
    int cbase = n0 + wc * 64 + r16;
#pragma unroll
    for (int m = 0; m < 4; ++m)
#pragma unroll
        for (int n = 0; n < 4; ++n)
#pragma unroll
            for (int r = 0; r < 4; ++r) {
                float v = acc[m][n][r];
                v = v > 0.f ? v : 0.f;
                out[(long)(rbase + m * 16 + r) * F_ + cbase + n * 16] = v;
            }
}

extern "C" void kernel_launch(void* const* d_in, const int* in_sizes, int n_in,
                              void* d_out, int out_size, void* d_ws, size_t ws_size,
                              hipStream_t stream) {
    const float* x  = (const float*)d_in[0];
    const float* Wd = (const float*)d_in[1];
    const float* Wp = (const float*)d_in[2];
    float* out = (float*)d_out;

    bf16_t* dw  = (bf16_t*)d_ws;                                  // M_*C_ bf16 = 62,914,560 B
    bf16_t* WpT = (bf16_t*)((char*)d_ws + (size_t)M_ * C_ * 2);   // + 131,072 B

    wp_transpose_kernel<<<F_, C_, 0, stream>>>(Wp, WpT);
    dw_conv_kernel<<<(H_ / 2) * (W_ / 2), 256, 0, stream>>>(x, Wd, dw);
    gemm_kernel<<<dim3(M_ / BM, F_ / BN), 256, 0, stream>>>(dw, WpT, out);
}

// Round 7
// 139.092 us; speedup vs baseline: 2.6495x; 1.0037x over previous
//
#include <hip/hip_runtime.h>
#include <hip/hip_bf16.h>

#define T_ 8
#define H_ 96
#define W_ 160
#define C_ 256
#define F_ 256
#define M_ (T_ * H_ * W_)   // 122880

typedef __bf16 bf16_t;
typedef __bf16 bf16x2 __attribute__((ext_vector_type(2)));
typedef __bf16 bf16x8 __attribute__((ext_vector_type(8)));
typedef float  f32x2  __attribute__((ext_vector_type(2)));
typedef float  f32x4  __attribute__((ext_vector_type(4)));

// ---------------- pass 0: WpT[f][c] = bf16(Wp[c][f]) ----------------
__global__ void wp_transpose_kernel(const float* __restrict__ Wp,
                                    bf16_t* __restrict__ WpT) {
    int f = blockIdx.x;   // 0..255
    int c = threadIdx.x;  // 0..255
    WpT[f * C_ + c] = (bf16_t)Wp[c * F_ + f];
}

// ---------------- pass 1: depthwise 3x3x3 conv, fp32 -> bf16 ----------------
// r6 structure, plus the decisive fix: an inline-asm memory-clobber fence
// between the 24-load batch and the FMA consume. The scheduler has sunk the
// loads into the consume loop in r3/r4/r6 (VGPR stuck at 64, ~42cy/vmem-instr
// serialization); a may-write-memory asm makes that sink ILLEGAL. No VGPR
// operand on the fence -> no forced waitcnt; loads drain during early FMAs.
// Live regs ~150 (54 wreg + 32 acc + 48 batch + addr) < 256 cap from (256,2).
__global__ __launch_bounds__(256, 2) void dw_conv_kernel(const float* __restrict__ x,
                                                         const float* __restrict__ Wd,
                                                         bf16_t* __restrict__ dw) {
    // XCD-chunked swizzle: grid 3840 % 8 == 0 -> bijective
    int nchunk = gridDim.x >> 3;
    int bb  = (blockIdx.x & 7) * nchunk + (blockIdx.x >> 3);
    int h2  = bb / (W_ / 2);
    int wq  = bb % (W_ / 2);
    int h0  = h2 * 2;
    int tid = threadIdx.x;
    int c   = (tid & 127) * 2;       // channel pair
    int w   = wq * 2 + (tid >> 7);   // wave-uniform

    // ---- weights: all 27 taps resident (54 VGPRs) ----
    f32x2 wreg[27];
#pragma unroll
    for (int k = 0; k < 27; ++k) wreg[k] = *(const f32x2*)&Wd[k * C_ + c];
    // fence: weight loads may not sink into the dh loop (would cross a clobber)
    asm volatile("" ::: "memory");

    f32x2 acc[2][8] = {};
    const int tstride = H_ * W_ * C_;

#pragma unroll
    for (int dh = -1; dh <= 2; ++dh) {
        int hh = h0 + dh;
        if (hh < 0 || hh >= H_) continue;          // wave-uniform

        // ---- batch-issue all 24 x loads for this dh (3 ww x 8 tt, f32x2) ----
        f32x2 v[3][8];
#pragma unroll
        for (int dwi = -1; dwi <= 1; ++dwi) {
            int ww = w + dwi;
            const float* px = x + (hh * W_ + ww) * C_ + c;
#pragma unroll
            for (int tt = 0; tt < 8; ++tt) {
                f32x2 vv = {};
                if ((unsigned)ww < (unsigned)W_)   // wave-uniform
                    vv = *(const f32x2*)&px[tt * tstride];
                v[dwi + 1][tt] = vv;
            }
        }
        // fence: loads above may NOT move below (scheduler sink now illegal)
        asm volatile("" ::: "memory");

        // ---- consume against resident weights ----
#pragma unroll
        for (int tt = 0; tt < 8; ++tt)
#pragma unroll
            for (int j = 0; j < 2; ++j) {
                int kh = dh + 1 - j;
                if (kh < 0 || kh > 2) continue;    // compile-time
#pragma unroll
                for (int kt = 0; kt < 3; ++kt) {
                    int to = tt + 1 - kt;
                    if (to < 0 || to >= 8) continue;  // compile-time
#pragma unroll
                    for (int kw = 0; kw < 3; ++kw)
                        acc[j][to] += v[kw][tt] * wreg[(kt * 3 + kh) * 3 + kw];
                }
            }
    }

#pragma unroll
    for (int j = 0; j < 2; ++j)
#pragma unroll
        for (int tt = 0; tt < 8; ++tt) {
            bf16x2 o;
            o[0] = (bf16_t)acc[j][tt][0];
            o[1] = (bf16_t)acc[j][tt][1];
            *(bf16x2*)&dw[((tt * H_ + (h0 + j)) * W_ + w) * C_ + c] = o;
        }
}

// ---------------- pass 2: GEMM [M,256]x[256,256] bf16 MFMA + ReLU ----------------
#define BM 128
#define BN 128
#define BK 32
#define LDSTR 40  // 32 + 8 pad: fragment ds_read_b128 2-way (free) instead of 8-way

__global__ __launch_bounds__(256) void gemm_kernel(const bf16_t* __restrict__ A,   // dw  [M][C]
                                                   const bf16_t* __restrict__ Bt,  // WpT [F][C] (n-major)
                                                   float* __restrict__ out) {      // [M][F]
    __shared__ __align__(16) bf16_t As[BM * LDSTR];
    __shared__ __align__(16) bf16_t Bs[BN * LDSTR];

    int m0   = blockIdx.x * BM;
    int n0   = blockIdx.y * BN;
    int tid  = threadIdx.x;
    int lane = tid & 63;
    int wid  = tid >> 6;
    int wr   = wid >> 1;   // 0..1
    int wc   = wid & 1;    // 0..1
    int r16  = lane & 15;
    int kg   = lane >> 4;  // 0..3

    f32x4 acc[4][4] = {};

    for (int k0 = 0; k0 < C_; k0 += BK) {
        __syncthreads();
#pragma unroll
        for (int it = 0; it < 2; ++it) {
            int slot = tid + it * 256;       // 0..511
            int row  = slot >> 2;            // 0..127
            int seg  = slot & 3;             // 0..3 (8 bf16 each)
            uint4 va = *(const uint4*)&A[(long)(m0 + row) * C_ + k0 + seg * 8];
            *(uint4*)&As[row * LDSTR + seg * 8] = va;
            uint4 vb = *(const uint4*)&Bt[(n0 + row) * C_ + k0 + seg * 8];
            *(uint4*)&Bs[row * LDSTR + seg * 8] = vb;
        }
        __syncthreads();

        bf16x8 af[4], bfr[4];
#pragma unroll
        for (int m = 0; m < 4; ++m)
            af[m] = *(const bf16x8*)&As[(wr * 64 + m * 16 + r16) * LDSTR + kg * 8];
#pragma unroll
        for (int n = 0; n < 4; ++n)
            bfr[n] = *(const bf16x8*)&Bs[(wc * 64 + n * 16 + r16) * LDSTR + kg * 8];

#pragma unroll
        for (int m = 0; m < 4; ++m)
#pragma unroll
            for (int n = 0; n < 4; ++n)
                acc[m][n] = __builtin_amdgcn_mfma_f32_16x16x32_bf16(af[m], bfr[n], acc[m][n], 0, 0, 0);
    }

    // epilogue: ReLU + fp32 store.  D layout: row=(l>>4)*4+r, col=l&15
    int rbase = m0 + wr * 64 + kg * 4;
    int cbase = n0 + wc * 64 + r16;
#pragma unroll
    for (int m = 0; m < 4; ++m)
#pragma unroll
        for (int n = 0; n < 4; ++n)
#pragma unroll
            for (int r = 0; r < 4; ++r) {
                float v = acc[m][n][r];
                v = v > 0.f ? v : 0.f;
                out[(long)(rbase + m * 16 + r) * F_ + cbase + n * 16] = v;
            }
}

extern "C" void kernel_launch(void* const* d_in, const int* in_sizes, int n_in,
                              void* d_out, int out_size, void* d_ws, size_t ws_size,
                              hipStream_t stream) {
    const float* x  = (const float*)d_in[0];
    const float* Wd = (const float*)d_in[1];
    const float* Wp = (const float*)d_in[2];
    float* out = (float*)d_out;

    bf16_t* dw  = (bf16_t*)d_ws;                                  // M_*C_ bf16 = 62,914,560 B
    bf16_t* WpT = (bf16_t*)((char*)d_ws + (size_t)M_ * C_ * 2);   // + 131,072 B

    wp_transpose_kernel<<<F_, C_, 0, stream>>>(Wp, WpT);
    dw_conv_kernel<<<(H_ / 2) * (W_ / 2), 256, 0, stream>>>(x, Wd, dw);
    gemm_kernel<<<dim3(M_ / BM, F_ / BN), 256, 0, stream>>>(dw, WpT, out);
}

// Round 8
// 137.480 us; speedup vs baseline: 2.6806x; 1.0117x over previous
//
#include <hip/hip_runtime.h>
#include <hip/hip_bf16.h>

#define T_ 8
#define H_ 96
#define W_ 160
#define C_ 256
#define F_ 256
#define M_ (T_ * H_ * W_)   // 122880

typedef __bf16 bf16_t;
typedef __bf16 bf16x2 __attribute__((ext_vector_type(2)));
typedef __bf16 bf16x8 __attribute__((ext_vector_type(8)));
typedef float  f32x2  __attribute__((ext_vector_type(2)));
typedef float  f32x4  __attribute__((ext_vector_type(4)));

// ---------------- pass 0: WpT[f][c] = bf16(Wp[c][f]) ----------------
__global__ void wp_transpose_kernel(const float* __restrict__ Wp,
                                    bf16_t* __restrict__ WpT) {
    int f = blockIdx.x;   // 0..255
    int c = threadIdx.x;  // 0..255
    WpT[f * C_ + c] = (bf16_t)Wp[c * F_ + f];
}

// ---------------- pass 1: depthwise 3x3x3 conv, fp32 -> bf16 ----------------
// r7 failed because a "memory" clobber doesn't order register-only FMAs —
// they hoisted above the fence and re-serialized the loads (VGPR stuck 64,
// ~1.5 loads in flight by Little's law). This round the wall is a DATA
// dependency: one volatile asm with "+v" on all 24 loaded values (and one on
// the 27 weights). Loads feed the asm; FMAs consume the asm outputs; 48+54
// VGPRs forced live -> batch must exist. Expect one vmcnt(0) at the wall:
// issue-24 -> wait -> compute.
__global__ __launch_bounds__(256, 2) void dw_conv_kernel(const float* __restrict__ x,
                                                         const float* __restrict__ Wd,
                                                         bf16_t* __restrict__ dw) {
    // XCD-chunked swizzle: grid 3840 % 8 == 0 -> bijective
    int nchunk = gridDim.x >> 3;
    int bb  = (blockIdx.x & 7) * nchunk + (blockIdx.x >> 3);
    int h2  = bb / (W_ / 2);
    int wq  = bb % (W_ / 2);
    int h0  = h2 * 2;
    int tid = threadIdx.x;
    int c   = (tid & 127) * 2;       // channel pair
    int w   = wq * 2 + (tid >> 7);   // wave-uniform

    // ---- weights: all 27 taps resident (54 VGPRs), pinned by asm wall ----
    f32x2 wreg[27];
#pragma unroll
    for (int k = 0; k < 27; ++k) wreg[k] = *(const f32x2*)&Wd[k * C_ + c];
    asm volatile(""
        : "+v"(wreg[0]),  "+v"(wreg[1]),  "+v"(wreg[2]),  "+v"(wreg[3]),
          "+v"(wreg[4]),  "+v"(wreg[5]),  "+v"(wreg[6]),  "+v"(wreg[7]),
          "+v"(wreg[8]),  "+v"(wreg[9]),  "+v"(wreg[10]), "+v"(wreg[11]),
          "+v"(wreg[12]), "+v"(wreg[13]), "+v"(wreg[14]), "+v"(wreg[15]),
          "+v"(wreg[16]), "+v"(wreg[17]), "+v"(wreg[18]), "+v"(wreg[19]),
          "+v"(wreg[20]), "+v"(wreg[21]), "+v"(wreg[22]), "+v"(wreg[23]),
          "+v"(wreg[24]), "+v"(wreg[25]), "+v"(wreg[26]));

    f32x2 acc[2][8] = {};
    const int tstride = H_ * W_ * C_;

#pragma unroll
    for (int dh = -1; dh <= 2; ++dh) {
        int hh = h0 + dh;
        if (hh < 0 || hh >= H_) continue;          // wave-uniform

        // ---- batch-issue all 24 x loads for this dh (3 ww x 8 tt, f32x2) ----
        f32x2 v[3][8];
#pragma unroll
        for (int dwi = -1; dwi <= 1; ++dwi) {
            int ww = w + dwi;
            const float* px = x + (hh * W_ + ww) * C_ + c;
#pragma unroll
            for (int tt = 0; tt < 8; ++tt) {
                f32x2 vv = {};
                if ((unsigned)ww < (unsigned)W_)   // wave-uniform
                    vv = *(const f32x2*)&px[tt * tstride];
                v[dwi + 1][tt] = vv;
            }
        }
        // DATA-DEPENDENCY wall: all 24 values must be live here; FMAs below
        // consume the asm outputs and cannot hoist above it.
        asm volatile(""
            : "+v"(v[0][0]), "+v"(v[0][1]), "+v"(v[0][2]), "+v"(v[0][3]),
              "+v"(v[0][4]), "+v"(v[0][5]), "+v"(v[0][6]), "+v"(v[0][7]),
              "+v"(v[1][0]), "+v"(v[1][1]), "+v"(v[1][2]), "+v"(v[1][3]),
              "+v"(v[1][4]), "+v"(v[1][5]), "+v"(v[1][6]), "+v"(v[1][7]),
              "+v"(v[2][0]), "+v"(v[2][1]), "+v"(v[2][2]), "+v"(v[2][3]),
              "+v"(v[2][4]), "+v"(v[2][5]), "+v"(v[2][6]), "+v"(v[2][7]));

        // ---- consume against resident weights ----
#pragma unroll
        for (int tt = 0; tt < 8; ++tt)
#pragma unroll
            for (int j = 0; j < 2; ++j) {
                int kh = dh + 1 - j;
                if (kh < 0 || kh > 2) continue;    // compile-time
#pragma unroll
                for (int kt = 0; kt < 3; ++kt) {
                    int to = tt + 1 - kt;
                    if (to < 0 || to >= 8) continue;  // compile-time
#pragma unroll
                    for (int kw = 0; kw < 3; ++kw)
                        acc[j][to] += v[kw][tt] * wreg[(kt * 3 + kh) * 3 + kw];
                }
            }
    }

#pragma unroll
    for (int j = 0; j < 2; ++j)
#pragma unroll
        for (int tt = 0; tt < 8; ++tt) {
            bf16x2 o;
            o[0] = (bf16_t)acc[j][tt][0];
            o[1] = (bf16_t)acc[j][tt][1];
            *(bf16x2*)&dw[((tt * H_ + (h0 + j)) * W_ + w) * C_ + c] = o;
        }
}

// ---------------- pass 2: GEMM [M,256]x[256,256] bf16 MFMA + ReLU ----------------
#define BM 128
#define BN 128
#define BK 32
#define LDSTR 40  // 32 + 8 pad: fragment ds_read_b128 2-way (free) instead of 8-way

__global__ __launch_bounds__(256) void gemm_kernel(const bf16_t* __restrict__ A,   // dw  [M][C]
                                                   const bf16_t* __restrict__ Bt,  // WpT [F][C] (n-major)
                                                   float* __restrict__ out) {      // [M][F]
    __shared__ __align__(16) bf16_t As[BM * LDSTR];
    __shared__ __align__(16) bf16_t Bs[BN * LDSTR];

    int m0   = blockIdx.x * BM;
    int n0   = blockIdx.y * BN;
    int tid  = threadIdx.x;
    int lane = tid & 63;
    int wid  = tid >> 6;
    int wr   = wid >> 1;   // 0..1
    int wc   = wid & 1;    // 0..1
    int r16  = lane & 15;
    int kg   = lane >> 4;  // 0..3

    f32x4 acc[4][4] = {};

    for (int k0 = 0; k0 < C_; k0 += BK) {
        __syncthreads();
#pragma unroll
        for (int it = 0; it < 2; ++it) {
            int slot = tid + it * 256;       // 0..511
            int row  = slot >> 2;            // 0..127
            int seg  = slot & 3;             // 0..3 (8 bf16 each)
            uint4 va = *(const uint4*)&A[(long)(m0 + row) * C_ + k0 + seg * 8];
            *(uint4*)&As[row * LDSTR + seg * 8] = va;
            uint4 vb = *(const uint4*)&Bt[(n0 + row) * C_ + k0 + seg * 8];
            *(uint4*)&Bs[row * LDSTR + seg * 8] = vb;
        }
        __syncthreads();

        bf16x8 af[4], bfr[4];
#pragma unroll
        for (int m = 0; m < 4; ++m)
            af[m] = *(const bf16x8*)&As[(wr * 64 + m * 16 + r16) * LDSTR + kg * 8];
#pragma unroll
        for (int n = 0; n < 4; ++n)
            bfr[n] = *(const bf16x8*)&Bs[(wc * 64 + n * 16 + r16) * LDSTR + kg * 8];

#pragma unroll
        for (int m = 0; m < 4; ++m)
#pragma unroll
            for (int n = 0; n < 4; ++n)
                acc[m][n] = __builtin_amdgcn_mfma_f32_16x16x32_bf16(af[m], bfr[n], acc[m][n], 0, 0, 0);
    }

    // epilogue: ReLU + fp32 store.  D layout: row=(l>>4)*4+r, col=l&15
    int rbase = m0 + wr * 64 + kg * 4;
    int cbase = n0 + wc * 64 + r16;
#pragma unroll
    for (int m = 0; m < 4; ++m)
#pragma unroll
        for (int n = 0; n < 4; ++n)
#pragma unroll
            for (int r = 0; r < 4; ++r) {
                float v = acc[m][n][r];
                v = v > 0.f ? v : 0.f;
                out[(long)(rbase + m * 16 + r) * F_ + cbase + n * 16] = v;
            }
}

extern "C" void kernel_launch(void* const* d_in, const int* in_sizes, int n_in,
                              void* d_out, int out_size, void* d_ws, size_t ws_size,
                              hipStream_t stream) {
    const float* x  = (const float*)d_in[0];
    const float* Wd = (const float*)d_in[1];
    const float* Wp = (const float*)d_in[2];
    float* out = (float*)d_out;

    bf16_t* dw  = (bf16_t*)d_ws;                                  // M_*C_ bf16 = 62,914,560 B
    bf16_t* WpT = (bf16_t*)((char*)d_ws + (size_t)M_ * C_ * 2);   // + 131,072 B

    wp_transpose_kernel<<<F_, C_, 0, stream>>>(Wp, WpT);
    dw_conv_kernel<<<(H_ / 2) * (W_ / 2), 256, 0, stream>>>(x, Wd, dw);
    gemm_kernel<<<dim3(M_ / BM, F_ / BN), 256, 0, stream>>>(dw, WpT, out);
}